// Round 7
// baseline (513.729 us; speedup 1.0000x reference)
//
#include <hip/hip_runtime.h>
#include <hip/hip_bf16.h>

constexpr int NN = 40000;
constexpr int NE = 640000;
constexpr int D  = 128;
constexpr int NG = 128;

__device__ __forceinline__ ushort f2bf(float x) {
  union { float f; unsigned u; } c{x};
  const unsigned r = (c.u + 0x7FFFu + ((c.u >> 16) & 1u)) >> 16;  // RNE
  return (ushort)r;
}

// ---------------------------------------------------------------------------
// One fused converter: feat (f32->bf16) + the three W matrices.
// ---------------------------------------------------------------------------
constexpr int FEAT4 = NN * D / 4;   // 1,280,000 float4s
constexpr int W4    = D * D / 4;    // 4,096 float4s per W

__global__ __launch_bounds__(256)
void cvt_all(const float* __restrict__ feat, const float* __restrict__ w0,
             const float* __restrict__ w1, const float* __restrict__ w2,
             ushort* __restrict__ featb, ushort* __restrict__ Wb) {
  const int i = blockIdx.x * 256 + threadIdx.x;
  const float* src; ushort* dst; int idx;
  if (i < FEAT4) { src = feat; dst = featb; idx = i; }
  else if (i < FEAT4 + 3 * W4) {
    const int j = i - FEAT4;
    const int ws = j >> 12;            // j / 4096
    idx = j & (W4 - 1);
    src = ws == 0 ? w0 : (ws == 1 ? w1 : w2);
    dst = Wb + (size_t)ws * D * D;
  } else return;
  const float4 v = ((const float4*)src)[idx];
  ushort4 p;
  p.x = f2bf(v.x); p.y = f2bf(v.y); p.z = f2bf(v.z); p.w = f2bf(v.w);
  ((ushort4*)dst)[idx] = p;
}

// ---------------------------------------------------------------------------
// MFMA GEMM: tmp[n][d] = sum_k A[n][k] * W[d][k], bf16 in/out.
// 256 thr = 4 waves, 16 rows/wave, 64 rows/block; fragments direct from
// global (W is 32KB -> L1/L2 resident). C/D: col=lane&15, row=(lane>>4)*4+q.
// ---------------------------------------------------------------------------
using short8 = __attribute__((ext_vector_type(8))) short;
using f32x4  = __attribute__((ext_vector_type(4))) float;

__global__ __launch_bounds__(256)
void gemm_mfma(const ushort* __restrict__ A, const ushort* __restrict__ Wb,
               ushort* __restrict__ out) {
  const int tid  = threadIdx.x;
  const int wave = tid >> 6, lane = tid & 63;
  const int n0 = blockIdx.x * 64 + wave * 16;
  const int r  = lane & 15, kg = lane >> 4;

  short8 afr[4];
  const ushort* arow = A + (size_t)(n0 + r) * D + kg * 8;
#pragma unroll
  for (int kt = 0; kt < 4; ++kt)
    afr[kt] = *(const short8*)(arow + kt * 32);

#pragma unroll
  for (int ct = 0; ct < 8; ++ct) {
    f32x4 acc = {0.f, 0.f, 0.f, 0.f};
    const ushort* wrow = Wb + (size_t)(ct * 16 + r) * D + kg * 8;
#pragma unroll
    for (int kt = 0; kt < 4; ++kt) {
      const short8 bfr = *(const short8*)(wrow + kt * 32);
      acc = __builtin_amdgcn_mfma_f32_16x16x32_bf16(afr[kt], bfr, acc, 0, 0, 0);
    }
#pragma unroll
    for (int q = 0; q < 4; ++q) {
      const int m = kg * 4 + q;
      out[(size_t)(n0 + m) * D + ct * 16 + r] = f2bf(acc[q]);
    }
  }
}

// ---------------------------------------------------------------------------
// CSR build: histogram, 2-dispatch scan, packed fill (uint2 per edge).
// ---------------------------------------------------------------------------
__global__ void hist_k(const int* __restrict__ col, int* __restrict__ cnt) {
  const int e = blockIdx.x * blockDim.x + threadIdx.x;
  if (e < NE) atomicAdd(&cnt[col[e]], 1);
}

constexpr int SCAN_B = 1024;
constexpr int SCAN_NB = (NN + SCAN_B - 1) / SCAN_B;  // 40

__global__ __launch_bounds__(SCAN_B)
void scan_part(const int* __restrict__ cnt, int* __restrict__ off,
               int* __restrict__ bsum) {
  __shared__ int buf[SCAN_B];
  const int tid = threadIdx.x;
  const int i = blockIdx.x * SCAN_B + tid;
  const int v = (i < NN) ? cnt[i] : 0;
  buf[tid] = v;
  __syncthreads();
  for (int s = 1; s < SCAN_B; s <<= 1) {
    const int t = (tid >= s) ? buf[tid - s] : 0;
    __syncthreads();
    buf[tid] += t;
    __syncthreads();
  }
  if (i < NN) off[i] = buf[tid] - v;
  if (tid == SCAN_B - 1) bsum[blockIdx.x] = buf[tid];
}

// scan of 40 block sums recomputed redundantly per block (1 wave), then add.
__global__ __launch_bounds__(SCAN_B)
void scan_add(int* __restrict__ off, const int* __restrict__ bsum,
              int* __restrict__ cur) {
  __shared__ int boff_s;
  const int tid = threadIdx.x;
  if (tid < 64) {
    int v = (tid < SCAN_NB) ? bsum[tid] : 0;
    const int mine = v;
#pragma unroll
    for (int s = 1; s < 64; s <<= 1) {
      const int t = __shfl_up(v, s);
      if (tid >= s) v += t;
    }
    if (tid == (int)blockIdx.x) boff_s = v - mine;
    if (blockIdx.x == 0 && tid == SCAN_NB - 1) off[NN] = v;  // total = NE
  }
  __syncthreads();
  const int i = blockIdx.x * SCAN_B + tid;
  if (i < NN) {
    const int v = off[i] + boff_s;
    off[i] = v;
    cur[i] = v;
  }
}

__global__ void fill_k(const int* __restrict__ row, const int* __restrict__ col,
                       const float* __restrict__ w, int* __restrict__ cur,
                       uint2* __restrict__ epk) {
  const int e = blockIdx.x * blockDim.x + threadIdx.x;
  if (e < NE) {
    const int p = atomicAdd(&cur[col[e]], 1);
    uint2 v;
    v.x = (unsigned)row[e];
    v.y = __float_as_uint(w[e]);
    epk[p] = v;
  }
}

// ---------------------------------------------------------------------------
// Gather (CSR, bf16 rows) + PReLU + fused graph pooling.
// One wave per node; lane i loads edge-meta epk[lo+i] (coalesced 8B);
// src/weight broadcast via readlane; row loads in batches of 16 independent
// gathers (tail lanes padded src=0,w=0 -> L1-hit dummy loads contribute 0).
// Pool: per-lane 2x atomicAdd into hg[batch[wid]] (hg pre-zeroed).
// ---------------------------------------------------------------------------
__global__ __launch_bounds__(256)
void gather_prelu(const ushort* __restrict__ tmp, const int* __restrict__ off,
                  const uint2* __restrict__ epk, const float* __restrict__ aP,
                  const int* __restrict__ batch, float* __restrict__ hg,
                  int layer, ushort* __restrict__ hb, float* __restrict__ hout) {
  const int wid  = (blockIdx.x * 256 + threadIdx.x) >> 6;
  const int lane = threadIdx.x & 63;
  if (wid >= NN) return;
  const int lo = off[wid], hi = off[wid + 1];
  const int deg = hi - lo;
  float ax = 0.f, ay = 0.f;

  for (int base = 0; base < deg; base += 64) {
    const int rem = deg - base;
    uint2 meta = make_uint2(0u, 0u);
    if (lane < rem) meta = epk[lo + base + lane];
    const int cnt = rem < 64 ? rem : 64;
    for (int j0 = 0; j0 < cnt; j0 += 16) {
      unsigned v[16]; float w[16];
#pragma unroll
      for (int j = 0; j < 16; ++j) {
        const int src = __builtin_amdgcn_readlane((int)meta.x, j0 + j);
        w[j] = __uint_as_float(__builtin_amdgcn_readlane((int)meta.y, j0 + j));
        v[j] = *(const unsigned*)(tmp + (size_t)src * D + lane * 2);
      }
#pragma unroll
      for (int j = 0; j < 16; ++j) {
        ax += __uint_as_float(v[j] << 16) * w[j];
        ay += __uint_as_float(v[j] & 0xFFFF0000u) * w[j];
      }
    }
  }
  const float alpha = aP[0];
  ax = ax >= 0.f ? ax : alpha * ax;
  ay = ay >= 0.f ? ay : alpha * ay;

  union { unsigned u; ushort s[2]; } pk;
  pk.s[0] = f2bf(ax); pk.s[1] = f2bf(ay);
  *(unsigned*)(hb + (size_t)wid * D + lane * 2) = pk.u;
  if (hout)
    *(float2*)(hout + (size_t)wid * D + lane * 2) = make_float2(ax, ay);

  const int g = batch[wid];
  float* dst = hg + (size_t)g * (3 * D) + layer * D + lane * 2;
  atomicAdd(dst, ax);
  atomicAdd(dst + 1, ay);
}

// ---------------------------------------------------------------------------
extern "C" void kernel_launch(void* const* d_in, const int* in_sizes, int n_in,
                              void* d_out, int out_size, void* d_ws, size_t ws_size,
                              hipStream_t stream) {
  const float* feat    = (const float*)d_in[0];
  const float* eweight = (const float*)d_in[1];
  const float* W[3]    = {(const float*)d_in[2], (const float*)d_in[3], (const float*)d_in[4]};
  const float* a[3]    = {(const float*)d_in[5], (const float*)d_in[6], (const float*)d_in[7]};
  const int*   eidx    = (const int*)d_in[8];
  const int*   batch   = (const int*)d_in[9];
  const int*   erow = eidx;
  const int*   ecol = eidx + NE;

  char* ws = (char*)d_ws;
  ushort* tmp   = (ushort*)(ws);               // 10,240,000 B (bf16 NN x D)
  ushort* hb    = (ushort*)(ws + 10240000);    // 10,240,000 B (bf16 h)
  ushort* featb = (ushort*)(ws + 20480000);    // 10,240,000 B (bf16 feat)
  int*    cnt   = (int*)(ws + 30720000);       //    160,000 B
  int*    off   = (int*)(ws + 30880000);       //    160,004 B
  int*    cur   = (int*)(ws + 31040064);       //    160,000 B
  uint2*  epk   = (uint2*)(ws + 31200064);     //  5,120,000 B
  int*    bsum  = (int*)(ws + 36320064);       //        160 B
  ushort* Wb    = (ushort*)(ws + 36320384);    //     98,304 B  (3 x 128 x 128)

  float* hout = (float*)d_out;                 // NN x D (f32)
  float* hg   = hout + (size_t)NN * D;         // NG x 3D

  hipMemsetAsync(cnt, 0, NN * sizeof(int), stream);
  hipMemsetAsync(hg, 0, (size_t)NG * 3 * D * sizeof(float), stream);

  hist_k<<<(NE + 255) / 256, 256, 0, stream>>>(ecol, cnt);
  scan_part<<<SCAN_NB, SCAN_B, 0, stream>>>(cnt, off, bsum);
  scan_add<<<SCAN_NB, SCAN_B, 0, stream>>>(off, bsum, cur);
  fill_k<<<(NE + 255) / 256, 256, 0, stream>>>(erow, ecol, eweight, cur, epk);
  cvt_all<<<(FEAT4 + 3 * W4 + 255) / 256, 256, 0, stream>>>(
      feat, W[0], W[1], W[2], featb, Wb);

  const ushort* in = featb;
  for (int l = 0; l < 3; ++l) {
    gemm_mfma<<<NN / 64, 256, 0, stream>>>(in, Wb + (size_t)l * D * D, tmp);
    gather_prelu<<<(NN * 64 + 255) / 256, 256, 0, stream>>>(
        tmp, off, epk, a[l], batch, hg, l, hb, (l == 2) ? hout : nullptr);
    in = hb;
  }
}

// Round 8
// 330.782 us; speedup vs baseline: 1.5531x; 1.5531x over previous
//
#include <hip/hip_runtime.h>
#include <hip/hip_bf16.h>

constexpr int NN = 40000;
constexpr int NE = 640000;
constexpr int D  = 128;
constexpr int NG = 128;

__device__ __forceinline__ ushort f2bf(float x) {
  union { float f; unsigned u; } c{x};
  const unsigned r = (c.u + 0x7FFFu + ((c.u >> 16) & 1u)) >> 16;  // RNE
  return (ushort)r;
}
__device__ __forceinline__ float bf2f(ushort b) {
  return __uint_as_float(((unsigned)b) << 16);
}

// ---------------------------------------------------------------------------
// One fused converter: feat (f32->bf16) + the three W matrices.
// ---------------------------------------------------------------------------
constexpr int FEAT4 = NN * D / 4;   // 1,280,000 float4s
constexpr int W4    = D * D / 4;    // 4,096 float4s per W

__global__ __launch_bounds__(256)
void cvt_all(const float* __restrict__ feat, const float* __restrict__ w0,
             const float* __restrict__ w1, const float* __restrict__ w2,
             ushort* __restrict__ featb, ushort* __restrict__ Wb) {
  const int i = blockIdx.x * 256 + threadIdx.x;
  const float* src; ushort* dst; int idx;
  if (i < FEAT4) { src = feat; dst = featb; idx = i; }
  else if (i < FEAT4 + 3 * W4) {
    const int j = i - FEAT4;
    const int ws = j >> 12;            // j / 4096
    idx = j & (W4 - 1);
    src = ws == 0 ? w0 : (ws == 1 ? w1 : w2);
    dst = Wb + (size_t)ws * D * D;
  } else return;
  const float4 v = ((const float4*)src)[idx];
  ushort4 p;
  p.x = f2bf(v.x); p.y = f2bf(v.y); p.z = f2bf(v.z); p.w = f2bf(v.w);
  ((ushort4*)dst)[idx] = p;
}

// ---------------------------------------------------------------------------
// MFMA GEMM: tmp[n][d] = sum_k A[n][k] * W[d][k], bf16 in/out.
// 256 thr = 4 waves, 16 rows/wave, 64 rows/block; fragments direct from
// global (W is 32KB -> L1/L2 resident). C/D: col=lane&15, row=(lane>>4)*4+q.
// ---------------------------------------------------------------------------
using short8 = __attribute__((ext_vector_type(8))) short;
using f32x4  = __attribute__((ext_vector_type(4))) float;

__global__ __launch_bounds__(256)
void gemm_mfma(const ushort* __restrict__ A, const ushort* __restrict__ Wb,
               ushort* __restrict__ out) {
  const int tid  = threadIdx.x;
  const int wave = tid >> 6, lane = tid & 63;
  const int n0 = blockIdx.x * 64 + wave * 16;
  const int r  = lane & 15, kg = lane >> 4;

  short8 afr[4];
  const ushort* arow = A + (size_t)(n0 + r) * D + kg * 8;
#pragma unroll
  for (int kt = 0; kt < 4; ++kt)
    afr[kt] = *(const short8*)(arow + kt * 32);

#pragma unroll
  for (int ct = 0; ct < 8; ++ct) {
    f32x4 acc = {0.f, 0.f, 0.f, 0.f};
    const ushort* wrow = Wb + (size_t)(ct * 16 + r) * D + kg * 8;
#pragma unroll
    for (int kt = 0; kt < 4; ++kt) {
      const short8 bfr = *(const short8*)(wrow + kt * 32);
      acc = __builtin_amdgcn_mfma_f32_16x16x32_bf16(afr[kt], bfr, acc, 0, 0, 0);
    }
#pragma unroll
    for (int q = 0; q < 4; ++q) {
      const int m = kg * 4 + q;
      out[(size_t)(n0 + m) * D + ct * 16 + r] = f2bf(acc[q]);
    }
  }
}

// ---------------------------------------------------------------------------
// CSR build: histogram, 2-dispatch scan, packed fill (uint2 per edge).
// ---------------------------------------------------------------------------
__global__ void hist_k(const int* __restrict__ col, int* __restrict__ cnt) {
  const int e = blockIdx.x * blockDim.x + threadIdx.x;
  if (e < NE) atomicAdd(&cnt[col[e]], 1);
}

constexpr int SCAN_B = 1024;
constexpr int SCAN_NB = (NN + SCAN_B - 1) / SCAN_B;  // 40

__global__ __launch_bounds__(SCAN_B)
void scan_part(const int* __restrict__ cnt, int* __restrict__ off,
               int* __restrict__ bsum) {
  __shared__ int buf[SCAN_B];
  const int tid = threadIdx.x;
  const int i = blockIdx.x * SCAN_B + tid;
  const int v = (i < NN) ? cnt[i] : 0;
  buf[tid] = v;
  __syncthreads();
  for (int s = 1; s < SCAN_B; s <<= 1) {
    const int t = (tid >= s) ? buf[tid - s] : 0;
    __syncthreads();
    buf[tid] += t;
    __syncthreads();
  }
  if (i < NN) off[i] = buf[tid] - v;
  if (tid == SCAN_B - 1) bsum[blockIdx.x] = buf[tid];
}

// scan of 40 block sums recomputed redundantly per block (1 wave), then add.
__global__ __launch_bounds__(SCAN_B)
void scan_add(int* __restrict__ off, const int* __restrict__ bsum,
              int* __restrict__ cur) {
  __shared__ int boff_s;
  const int tid = threadIdx.x;
  if (tid < 64) {
    int v = (tid < SCAN_NB) ? bsum[tid] : 0;
    const int mine = v;
#pragma unroll
    for (int s = 1; s < 64; s <<= 1) {
      const int t = __shfl_up(v, s);
      if (tid >= s) v += t;
    }
    if (tid == (int)blockIdx.x) boff_s = v - mine;
    if (blockIdx.x == 0 && tid == SCAN_NB - 1) off[NN] = v;  // total = NE
  }
  __syncthreads();
  const int i = blockIdx.x * SCAN_B + tid;
  if (i < NN) {
    const int v = off[i] + boff_s;
    off[i] = v;
    cur[i] = v;
  }
}

__global__ void fill_k(const int* __restrict__ row, const int* __restrict__ col,
                       const float* __restrict__ w, int* __restrict__ cur,
                       uint2* __restrict__ epk) {
  const int e = blockIdx.x * blockDim.x + threadIdx.x;
  if (e < NE) {
    const int p = atomicAdd(&cur[col[e]], 1);
    uint2 v;
    v.x = (unsigned)row[e];
    v.y = __float_as_uint(w[e]);
    epk[p] = v;
  }
}

// ---------------------------------------------------------------------------
// Gather (CSR, bf16 rows) + PReLU. One wave per node; lane i loads edge-meta
// epk[lo+i] (coalesced 8B); src/weight broadcast via readlane; row loads in
// batches of 16 independent gathers (tail padded src=0,w=0 -> L1-hit dummy
// loads contribute 0). Writes bf16 h (always) + f32 h (final layer only).
// NO fused pooling: global atomics into the tiny hg array serialize
// (~312 adds/address across XCDs) — measured +70µs/layer in round 7.
// ---------------------------------------------------------------------------
__global__ __launch_bounds__(256)
void gather_prelu(const ushort* __restrict__ tmp, const int* __restrict__ off,
                  const uint2* __restrict__ epk, const float* __restrict__ aP,
                  ushort* __restrict__ hb, float* __restrict__ hout) {
  const int wid  = (blockIdx.x * 256 + threadIdx.x) >> 6;
  const int lane = threadIdx.x & 63;
  if (wid >= NN) return;
  const int lo = off[wid], hi = off[wid + 1];
  const int deg = hi - lo;
  float ax = 0.f, ay = 0.f;

  for (int base = 0; base < deg; base += 64) {
    const int rem = deg - base;
    uint2 meta = make_uint2(0u, 0u);
    if (lane < rem) meta = epk[lo + base + lane];
    const int cnt = rem < 64 ? rem : 64;
    for (int j0 = 0; j0 < cnt; j0 += 16) {
      unsigned v[16]; float w[16];
#pragma unroll
      for (int j = 0; j < 16; ++j) {
        const int src = __builtin_amdgcn_readlane((int)meta.x, j0 + j);
        w[j] = __uint_as_float(__builtin_amdgcn_readlane((int)meta.y, j0 + j));
        v[j] = *(const unsigned*)(tmp + (size_t)src * D + lane * 2);
      }
#pragma unroll
      for (int j = 0; j < 16; ++j) {
        ax += __uint_as_float(v[j] << 16) * w[j];
        ay += __uint_as_float(v[j] & 0xFFFF0000u) * w[j];
      }
    }
  }
  const float alpha = aP[0];
  ax = ax >= 0.f ? ax : alpha * ax;
  ay = ay >= 0.f ? ay : alpha * ay;

  union { unsigned u; ushort s[2]; } pk;
  pk.s[0] = f2bf(ax); pk.s[1] = f2bf(ay);
  *(unsigned*)(hb + (size_t)wid * D + lane * 2) = pk.u;
  if (hout)
    *(float2*)(hout + (size_t)wid * D + lane * 2) = make_float2(ax, ay);
}

// ---------------------------------------------------------------------------
// Graph pooling from bf16 h: block = 128 threads (one per column).
// ---------------------------------------------------------------------------
constexpr int POOL_SPLIT = 8;

__device__ __forceinline__ int lbound(const int* a, int n, int key) {
  int lo = 0, hi = n;
  while (lo < hi) { const int m = (lo + hi) >> 1; if (a[m] < key) lo = m + 1; else hi = m; }
  return lo;
}

__global__ __launch_bounds__(128)
void pool_k(const ushort* __restrict__ h, const int* __restrict__ batch,
            float* __restrict__ hg, int layer) {
  const int g    = blockIdx.x;
  const int part = blockIdx.y;
  const int tid  = threadIdx.x;
  const int lo = lbound(batch, NN, g);
  const int hi = lbound(batch, NN, g + 1);
  float acc = 0.f;
  for (int n = lo + part; n < hi; n += POOL_SPLIT)
    acc += bf2f(h[(size_t)n * D + tid]);
  atomicAdd(&hg[(size_t)g * (3 * D) + layer * D + tid], acc);
}

// ---------------------------------------------------------------------------
extern "C" void kernel_launch(void* const* d_in, const int* in_sizes, int n_in,
                              void* d_out, int out_size, void* d_ws, size_t ws_size,
                              hipStream_t stream) {
  const float* feat    = (const float*)d_in[0];
  const float* eweight = (const float*)d_in[1];
  const float* W[3]    = {(const float*)d_in[2], (const float*)d_in[3], (const float*)d_in[4]};
  const float* a[3]    = {(const float*)d_in[5], (const float*)d_in[6], (const float*)d_in[7]};
  const int*   eidx    = (const int*)d_in[8];
  const int*   batch   = (const int*)d_in[9];
  const int*   erow = eidx;
  const int*   ecol = eidx + NE;

  char* ws = (char*)d_ws;
  ushort* tmp   = (ushort*)(ws);               // 10,240,000 B (bf16 NN x D)
  ushort* hb    = (ushort*)(ws + 10240000);    // 10,240,000 B (bf16 h)
  ushort* featb = (ushort*)(ws + 20480000);    // 10,240,000 B (bf16 feat)
  int*    cnt   = (int*)(ws + 30720000);       //    160,000 B
  int*    off   = (int*)(ws + 30880000);       //    160,004 B
  int*    cur   = (int*)(ws + 31040064);       //    160,000 B
  uint2*  epk   = (uint2*)(ws + 31200064);     //  5,120,000 B
  int*    bsum  = (int*)(ws + 36320064);       //        160 B
  ushort* Wb    = (ushort*)(ws + 36320384);    //     98,304 B  (3 x 128 x 128)

  float* hout = (float*)d_out;                 // NN x D (f32)
  float* hg   = hout + (size_t)NN * D;         // NG x 3D

  hipMemsetAsync(cnt, 0, NN * sizeof(int), stream);
  hipMemsetAsync(hg, 0, (size_t)NG * 3 * D * sizeof(float), stream);

  hist_k<<<(NE + 255) / 256, 256, 0, stream>>>(ecol, cnt);
  scan_part<<<SCAN_NB, SCAN_B, 0, stream>>>(cnt, off, bsum);
  scan_add<<<SCAN_NB, SCAN_B, 0, stream>>>(off, bsum, cur);
  fill_k<<<(NE + 255) / 256, 256, 0, stream>>>(erow, ecol, eweight, cur, epk);
  cvt_all<<<(FEAT4 + 3 * W4 + 255) / 256, 256, 0, stream>>>(
      feat, W[0], W[1], W[2], featb, Wb);

  const ushort* in = featb;
  for (int l = 0; l < 3; ++l) {
    gemm_mfma<<<NN / 64, 256, 0, stream>>>(in, Wb + (size_t)l * D * D, tmp);
    gather_prelu<<<(NN * 64 + 255) / 256, 256, 0, stream>>>(
        tmp, off, epk, a[l], hb, (l == 2) ? hout : nullptr);
    pool_k<<<dim3(NG, POOL_SPLIT), 128, 0, stream>>>(hb, batch, hg, l);
    in = hb;
  }
}

// Round 9
// 298.195 us; speedup vs baseline: 1.7228x; 1.1093x over previous
//
#include <hip/hip_runtime.h>
#include <hip/hip_bf16.h>

constexpr int NN = 40000;
constexpr int NE = 640000;
constexpr int D  = 128;
constexpr int NG = 128;

__device__ __forceinline__ ushort f2bf(float x) {
  union { float f; unsigned u; } c{x};
  const unsigned r = (c.u + 0x7FFFu + ((c.u >> 16) & 1u)) >> 16;  // RNE
  return (ushort)r;
}
__device__ __forceinline__ float bf2f(ushort b) {
  return __uint_as_float(((unsigned)b) << 16);
}

using short8 = __attribute__((ext_vector_type(8))) short;
using f32x4  = __attribute__((ext_vector_type(4))) float;

// ---------------------------------------------------------------------------
// Fused: histogram of destinations + f32->bf16 conversion of feat and W[0..2].
// Blocks [0, HIST_B): hist atomics. Blocks [HIST_B, HIST_B+CVT_B): convert.
// ---------------------------------------------------------------------------
constexpr int FEAT4  = NN * D / 4;            // 1,280,000 float4s
constexpr int W4     = D * D / 4;             // 4,096 float4s per W
constexpr int HIST_B = (NE + 255) / 256;      // 2,500
constexpr int CVT_B  = (FEAT4 + 3 * W4 + 255) / 256;  // 5,049

__global__ __launch_bounds__(256)
void hist_cvt(const int* __restrict__ col, int* __restrict__ cnt,
              const float* __restrict__ feat, const float* __restrict__ w0,
              const float* __restrict__ w1, const float* __restrict__ w2,
              ushort* __restrict__ featb, ushort* __restrict__ Wb) {
  const int b = blockIdx.x;
  if (b < HIST_B) {
    const int e = b * 256 + threadIdx.x;
    if (e < NE) atomicAdd(&cnt[col[e]], 1);
    return;
  }
  const int i = (b - HIST_B) * 256 + threadIdx.x;
  const float* src; ushort* dst; int idx;
  if (i < FEAT4) { src = feat; dst = featb; idx = i; }
  else if (i < FEAT4 + 3 * W4) {
    const int j = i - FEAT4;
    const int ws = j >> 12;
    idx = j & (W4 - 1);
    src = ws == 0 ? w0 : (ws == 1 ? w1 : w2);
    dst = Wb + (size_t)ws * D * D;
  } else return;
  const float4 v = ((const float4*)src)[idx];
  ushort4 p;
  p.x = f2bf(v.x); p.y = f2bf(v.y); p.z = f2bf(v.z); p.w = f2bf(v.w);
  ((ushort4*)dst)[idx] = p;
}

// ---------------------------------------------------------------------------
// Single-pass decoupled-lookback exclusive scan of cnt[NN] -> off, cur.
// 40 blocks x 1024. bstate[b] = (flag<<24)|value; flag 1=aggregate 2=inclusive
// (values <= NE = 640000 < 2^24). Ticket assigns dense block order. All 40
// blocks co-resident on 256 CUs -> spin-wait is deadlock-free.
// ---------------------------------------------------------------------------
constexpr int SCAN_B  = 1024;
constexpr int SCAN_NB = (NN + SCAN_B - 1) / SCAN_B;  // 40

__global__ __launch_bounds__(SCAN_B)
void scan_onepass(const int* __restrict__ cnt, int* __restrict__ off,
                  int* __restrict__ cur, int* __restrict__ bstate,
                  int* __restrict__ ticket) {
  __shared__ int bid_s;
  if (threadIdx.x == 0) bid_s = atomicAdd(ticket, 1);
  __syncthreads();
  const int b   = bid_s;
  const int tid = threadIdx.x;
  const int i   = b * SCAN_B + tid;
  const int v   = (i < NN) ? cnt[i] : 0;

  __shared__ int buf[SCAN_B];
  buf[tid] = v;
  __syncthreads();
  for (int s = 1; s < SCAN_B; s <<= 1) {
    const int t = (tid >= s) ? buf[tid - s] : 0;
    __syncthreads();
    buf[tid] += t;
    __syncthreads();
  }
  const int total = buf[SCAN_B - 1];

  __shared__ int exc_s;
  if (tid == 0) {
    if (b == 0) {
      __hip_atomic_store(&bstate[0], (2 << 24) | total, __ATOMIC_RELEASE,
                         __HIP_MEMORY_SCOPE_AGENT);
      exc_s = 0;
    } else {
      __hip_atomic_store(&bstate[b], (1 << 24) | total, __ATOMIC_RELEASE,
                         __HIP_MEMORY_SCOPE_AGENT);
      int exc = 0, p = b - 1;
      while (true) {
        const int st = __hip_atomic_load(&bstate[p], __ATOMIC_ACQUIRE,
                                         __HIP_MEMORY_SCOPE_AGENT);
        const int fl = st >> 24;
        if (fl == 2) { exc += st & 0xFFFFFF; break; }
        if (fl == 1) { exc += st & 0xFFFFFF; --p; }
      }
      __hip_atomic_store(&bstate[b], (2 << 24) | (exc + total),
                         __ATOMIC_RELEASE, __HIP_MEMORY_SCOPE_AGENT);
      exc_s = exc;
    }
  }
  __syncthreads();
  const int e = exc_s + buf[tid] - v;   // global exclusive prefix
  if (i < NN) { off[i] = e; cur[i] = e; }
  if (b == SCAN_NB - 1 && tid == SCAN_B - 1) off[NN] = exc_s + total;  // = NE
}

// ---------------------------------------------------------------------------
// fill: scatter edges into CSR order, packed uint2 (src, weight-bits).
// ---------------------------------------------------------------------------
__global__ void fill_k(const int* __restrict__ row, const int* __restrict__ col,
                       const float* __restrict__ w, int* __restrict__ cur,
                       uint2* __restrict__ epk) {
  const int e = blockIdx.x * blockDim.x + threadIdx.x;
  if (e < NE) {
    const int p = atomicAdd(&cur[col[e]], 1);
    uint2 v;
    v.x = (unsigned)row[e];
    v.y = __float_as_uint(w[e]);
    epk[p] = v;
  }
}

// ---------------------------------------------------------------------------
// Pooling helper (16-way split, 256 threads: col = tid&127, part-bit = tid>>7)
// ---------------------------------------------------------------------------
__device__ __forceinline__ int lbound(const int* a, int n, int key) {
  int lo = 0, hi = n;
  while (lo < hi) { const int m = (lo + hi) >> 1; if (a[m] < key) lo = m + 1; else hi = m; }
  return lo;
}

__device__ __forceinline__ void pool_body(int pb, int tid,
                                          const ushort* __restrict__ h,
                                          const int* __restrict__ batch,
                                          float* __restrict__ hg, int layer) {
  const int g    = pb >> 3;
  const int part = ((pb & 7) << 1) | (tid >> 7);  // 0..15
  const int col  = tid & 127;
  const int lo = lbound(batch, NN, g);
  const int hi = lbound(batch, NN, g + 1);
  float acc = 0.f;
  for (int n = lo + part; n < hi; n += 16)
    acc += bf2f(h[(size_t)n * D + col]);
  atomicAdd(&hg[(size_t)g * (3 * D) + layer * D + col], acc);
}

// ---------------------------------------------------------------------------
// MFMA GEMM (+ optional piggy-backed pooling of the PREVIOUS layer's h).
// gemm blocks [0, GEMM_B): tmp[n][d] = sum_k A[n][k]*W[d][k], bf16 in/out.
// pool blocks [GEMM_B, GEMM_B+1024): pool hprev into hg[layer] (reads only).
// Pool free-rides: gemm alone fills 160K of 524K resident threads.
// ---------------------------------------------------------------------------
constexpr int GEMM_B = NN / 64;  // 625

__global__ __launch_bounds__(256)
void gemm_pool(const ushort* __restrict__ A, const ushort* __restrict__ Wb,
               ushort* __restrict__ out, const ushort* __restrict__ hprev,
               const int* __restrict__ batch, float* __restrict__ hg,
               int layer) {
  const int b = blockIdx.x;
  if (b >= GEMM_B) {
    pool_body(b - GEMM_B, threadIdx.x, hprev, batch, hg, layer);
    return;
  }
  const int tid  = threadIdx.x;
  const int wave = tid >> 6, lane = tid & 63;
  const int n0 = b * 64 + wave * 16;
  const int r  = lane & 15, kg = lane >> 4;

  short8 afr[4];
  const ushort* arow = A + (size_t)(n0 + r) * D + kg * 8;
#pragma unroll
  for (int kt = 0; kt < 4; ++kt)
    afr[kt] = *(const short8*)(arow + kt * 32);

#pragma unroll
  for (int ct = 0; ct < 8; ++ct) {
    f32x4 acc = {0.f, 0.f, 0.f, 0.f};
    const ushort* wrow = Wb + (size_t)(ct * 16 + r) * D + kg * 8;
#pragma unroll
    for (int kt = 0; kt < 4; ++kt) {
      const short8 bfr = *(const short8*)(wrow + kt * 32);
      acc = __builtin_amdgcn_mfma_f32_16x16x32_bf16(afr[kt], bfr, acc, 0, 0, 0);
    }
#pragma unroll
    for (int q = 0; q < 4; ++q) {
      const int m = kg * 4 + q;
      out[(size_t)(n0 + m) * D + ct * 16 + r] = f2bf(acc[q]);
    }
  }
}

// standalone pool for the final layer
__global__ __launch_bounds__(256)
void pool_k(const ushort* __restrict__ h, const int* __restrict__ batch,
            float* __restrict__ hg, int layer) {
  pool_body(blockIdx.x, threadIdx.x, h, batch, hg, layer);
}

// ---------------------------------------------------------------------------
// Gather (CSR, bf16 rows) + PReLU. One wave per node; lane i loads edge-meta
// epk[lo+i] (coalesced 8B); src/weight broadcast via readlane; row loads in
// batches of 16 independent gathers (tail padded src=0,w=0 -> L1-hit dummy
// loads contribute 0). Writes bf16 h (always) + f32 h (final layer only).
// NO fused pooling into this kernel: global atomics into the tiny hg array
// serialize (~312 adds/address across XCDs) — measured +70µs/layer (round 7).
// ---------------------------------------------------------------------------
__global__ __launch_bounds__(256)
void gather_prelu(const ushort* __restrict__ tmp, const int* __restrict__ off,
                  const uint2* __restrict__ epk, const float* __restrict__ aP,
                  ushort* __restrict__ hb, float* __restrict__ hout) {
  const int wid  = (blockIdx.x * 256 + threadIdx.x) >> 6;
  const int lane = threadIdx.x & 63;
  if (wid >= NN) return;
  const int lo = off[wid], hi = off[wid + 1];
  const int deg = hi - lo;
  float ax = 0.f, ay = 0.f;

  for (int base = 0; base < deg; base += 64) {
    const int rem = deg - base;
    uint2 meta = make_uint2(0u, 0u);
    if (lane < rem) meta = epk[lo + base + lane];
    const int cnt = rem < 64 ? rem : 64;
    for (int j0 = 0; j0 < cnt; j0 += 16) {
      unsigned v[16]; float w[16];
#pragma unroll
      for (int j = 0; j < 16; ++j) {
        const int src = __builtin_amdgcn_readlane((int)meta.x, j0 + j);
        w[j] = __uint_as_float(__builtin_amdgcn_readlane((int)meta.y, j0 + j));
        v[j] = *(const unsigned*)(tmp + (size_t)src * D + lane * 2);
      }
#pragma unroll
      for (int j = 0; j < 16; ++j) {
        ax += __uint_as_float(v[j] << 16) * w[j];
        ay += __uint_as_float(v[j] & 0xFFFF0000u) * w[j];
      }
    }
  }
  const float alpha = aP[0];
  ax = ax >= 0.f ? ax : alpha * ax;
  ay = ay >= 0.f ? ay : alpha * ay;

  union { unsigned u; ushort s[2]; } pk;
  pk.s[0] = f2bf(ax); pk.s[1] = f2bf(ay);
  *(unsigned*)(hb + (size_t)wid * D + lane * 2) = pk.u;
  if (hout)
    *(float2*)(hout + (size_t)wid * D + lane * 2) = make_float2(ax, ay);
}

// ---------------------------------------------------------------------------
extern "C" void kernel_launch(void* const* d_in, const int* in_sizes, int n_in,
                              void* d_out, int out_size, void* d_ws, size_t ws_size,
                              hipStream_t stream) {
  const float* feat    = (const float*)d_in[0];
  const float* eweight = (const float*)d_in[1];
  const float* W[3]    = {(const float*)d_in[2], (const float*)d_in[3], (const float*)d_in[4]};
  const float* a[3]    = {(const float*)d_in[5], (const float*)d_in[6], (const float*)d_in[7]};
  const int*   eidx    = (const int*)d_in[8];
  const int*   batch   = (const int*)d_in[9];
  const int*   erow = eidx;
  const int*   ecol = eidx + NE;

  char* ws = (char*)d_ws;
  ushort* tmp    = (ushort*)(ws);               // 10,240,000 B (bf16 NN x D)
  ushort* hb     = (ushort*)(ws + 10240000);    // 10,240,000 B (bf16 h)
  ushort* featb  = (ushort*)(ws + 20480000);    // 10,240,000 B (bf16 feat)
  int*    cnt    = (int*)(ws + 30720000);       //    160,000 B
  int*    bstate = (int*)(ws + 30880000);       //        160 B  (scan state)
  int*    ticket = (int*)(ws + 30880160);       //          4 B
  int*    off    = (int*)(ws + 30880192);       //    160,004 B
  int*    cur    = (int*)(ws + 31040256);       //    160,000 B
  uint2*  epk    = (uint2*)(ws + 31200320);     //  5,120,000 B
  ushort* Wb     = (ushort*)(ws + 36320320);    //     98,304 B  (3 x 128 x 128)

  float* hout = (float*)d_out;                 // NN x D (f32)
  float* hg   = hout + (size_t)NN * D;         // NG x 3D

  // zero cnt + bstate + ticket in one range; zero hg
  hipMemsetAsync(cnt, 0, 160164, stream);
  hipMemsetAsync(hg, 0, (size_t)NG * 3 * D * sizeof(float), stream);

  hist_cvt<<<HIST_B + CVT_B, 256, 0, stream>>>(ecol, cnt, feat, W[0], W[1], W[2],
                                               featb, Wb);
  scan_onepass<<<SCAN_NB, SCAN_B, 0, stream>>>(cnt, off, cur, bstate, ticket);
  fill_k<<<(NE + 255) / 256, 256, 0, stream>>>(erow, ecol, eweight, cur, epk);

  const ushort* in = featb;
  for (int l = 0; l < 3; ++l) {
    const int grid = (l == 0) ? GEMM_B : GEMM_B + 1024;  // piggy-back pool(l-1)
    gemm_pool<<<grid, 256, 0, stream>>>(in, Wb + (size_t)l * D * D, tmp,
                                        hb, batch, hg, l - 1);
    gather_prelu<<<(NN * 64 + 255) / 256, 256, 0, stream>>>(
        tmp, off, epk, a[l], hb, (l == 2) ? hout : nullptr);
    in = hb;
  }
  pool_k<<<1024, 256, 0, stream>>>(hb, batch, hg, 2);
}

// Round 10
// 290.902 us; speedup vs baseline: 1.7660x; 1.0251x over previous
//
#include <hip/hip_runtime.h>
#include <hip/hip_bf16.h>

constexpr int NN = 40000;
constexpr int NE = 640000;
constexpr int D  = 128;
constexpr int NG = 128;

__device__ __forceinline__ ushort f2bf(float x) {
  union { float f; unsigned u; } c{x};
  const unsigned r = (c.u + 0x7FFFu + ((c.u >> 16) & 1u)) >> 16;  // RNE
  return (ushort)r;
}
__device__ __forceinline__ float bf2f(ushort b) {
  return __uint_as_float(((unsigned)b) << 16);
}

using short8 = __attribute__((ext_vector_type(8))) short;
using f32x4  = __attribute__((ext_vector_type(4))) float;

// ---------------------------------------------------------------------------
// Fused: histogram + f32->bf16 conversion of feat/W + hg zeroing.
// Blocks [0,HIST_B): hist atomics. [HIST_B,HIST_B+CVT_B): convert.
// [HIST_B+CVT_B, +HGZ_B): zero hg (completes before first pool consumer).
// ---------------------------------------------------------------------------
constexpr int FEAT4  = NN * D / 4;            // 1,280,000 float4s
constexpr int W4     = D * D / 4;             // 4,096 float4s per W
constexpr int HIST_B = (NE + 255) / 256;      // 2,500
constexpr int CVT_B  = (FEAT4 + 3 * W4 + 255) / 256;  // 5,049
constexpr int HG4    = NG * 3 * D / 4;        // 12,288 float4s
constexpr int HGZ_B  = (HG4 + 255) / 256;     // 48

__global__ __launch_bounds__(256)
void hist_cvt(const int* __restrict__ col, int* __restrict__ cnt,
              const float* __restrict__ feat, const float* __restrict__ w0,
              const float* __restrict__ w1, const float* __restrict__ w2,
              ushort* __restrict__ featb, ushort* __restrict__ Wb,
              float* __restrict__ hg) {
  const int b = blockIdx.x;
  if (b < HIST_B) {
    const int e = b * 256 + threadIdx.x;
    if (e < NE) atomicAdd(&cnt[col[e]], 1);
    return;
  }
  if (b >= HIST_B + CVT_B) {
    const int i = (b - HIST_B - CVT_B) * 256 + threadIdx.x;
    if (i < HG4) ((float4*)hg)[i] = make_float4(0.f, 0.f, 0.f, 0.f);
    return;
  }
  const int i = (b - HIST_B) * 256 + threadIdx.x;
  const float* src; ushort* dst; int idx;
  if (i < FEAT4) { src = feat; dst = featb; idx = i; }
  else if (i < FEAT4 + 3 * W4) {
    const int j = i - FEAT4;
    const int ws = j >> 12;
    idx = j & (W4 - 1);
    src = ws == 0 ? w0 : (ws == 1 ? w1 : w2);
    dst = Wb + (size_t)ws * D * D;
  } else return;
  const float4 v = ((const float4*)src)[idx];
  ushort4 p;
  p.x = f2bf(v.x); p.y = f2bf(v.y); p.z = f2bf(v.z); p.w = f2bf(v.w);
  ((ushort4*)dst)[idx] = p;
}

// ---------------------------------------------------------------------------
// Single-pass decoupled-lookback exclusive scan of cnt[NN] -> off, cur.
// ---------------------------------------------------------------------------
constexpr int SCAN_B  = 1024;
constexpr int SCAN_NB = (NN + SCAN_B - 1) / SCAN_B;  // 40

__global__ __launch_bounds__(SCAN_B)
void scan_onepass(const int* __restrict__ cnt, int* __restrict__ off,
                  int* __restrict__ cur, int* __restrict__ bstate,
                  int* __restrict__ ticket) {
  __shared__ int bid_s;
  if (threadIdx.x == 0) bid_s = atomicAdd(ticket, 1);
  __syncthreads();
  const int b   = bid_s;
  const int tid = threadIdx.x;
  const int i   = b * SCAN_B + tid;
  const int v   = (i < NN) ? cnt[i] : 0;

  __shared__ int buf[SCAN_B];
  buf[tid] = v;
  __syncthreads();
  for (int s = 1; s < SCAN_B; s <<= 1) {
    const int t = (tid >= s) ? buf[tid - s] : 0;
    __syncthreads();
    buf[tid] += t;
    __syncthreads();
  }
  const int total = buf[SCAN_B - 1];

  __shared__ int exc_s;
  if (tid == 0) {
    if (b == 0) {
      __hip_atomic_store(&bstate[0], (2 << 24) | total, __ATOMIC_RELEASE,
                         __HIP_MEMORY_SCOPE_AGENT);
      exc_s = 0;
    } else {
      __hip_atomic_store(&bstate[b], (1 << 24) | total, __ATOMIC_RELEASE,
                         __HIP_MEMORY_SCOPE_AGENT);
      int exc = 0, p = b - 1;
      while (true) {
        const int st = __hip_atomic_load(&bstate[p], __ATOMIC_ACQUIRE,
                                         __HIP_MEMORY_SCOPE_AGENT);
        const int fl = st >> 24;
        if (fl == 2) { exc += st & 0xFFFFFF; break; }
        if (fl == 1) { exc += st & 0xFFFFFF; --p; }
      }
      __hip_atomic_store(&bstate[b], (2 << 24) | (exc + total),
                         __ATOMIC_RELEASE, __HIP_MEMORY_SCOPE_AGENT);
      exc_s = exc;
    }
  }
  __syncthreads();
  const int e = exc_s + buf[tid] - v;   // global exclusive prefix
  if (i < NN) { off[i] = e; cur[i] = e; }
  if (b == SCAN_NB - 1 && tid == SCAN_B - 1) off[NN] = exc_s + total;  // = NE
}

// ---------------------------------------------------------------------------
// fill: scatter edges into CSR order. 4B packed: (w_bf16 << 16) | src.
// src < 65536 (NN = 40000); weight quantized to bf16 (rel err 2^-9, same
// order as h's bf16 rounding).
// ---------------------------------------------------------------------------
__global__ void fill_k(const int* __restrict__ row, const int* __restrict__ col,
                       const float* __restrict__ w, int* __restrict__ cur,
                       unsigned* __restrict__ epk) {
  const int e = blockIdx.x * blockDim.x + threadIdx.x;
  if (e < NE) {
    const int p = atomicAdd(&cur[col[e]], 1);
    epk[p] = ((unsigned)f2bf(w[e]) << 16) | (unsigned)row[e];
  }
}

// ---------------------------------------------------------------------------
// Pooling helper (16-way split, 256 threads: col = tid&127, part-bit = tid>>7)
// ---------------------------------------------------------------------------
__device__ __forceinline__ int lbound(const int* a, int n, int key) {
  int lo = 0, hi = n;
  while (lo < hi) { const int m = (lo + hi) >> 1; if (a[m] < key) lo = m + 1; else hi = m; }
  return lo;
}

__device__ __forceinline__ void pool_body(int pb, int tid,
                                          const ushort* __restrict__ h,
                                          const int* __restrict__ batch,
                                          float* __restrict__ hg, int layer) {
  const int g    = pb >> 3;
  const int part = ((pb & 7) << 1) | (tid >> 7);  // 0..15
  const int col  = tid & 127;
  const int lo = lbound(batch, NN, g);
  const int hi = lbound(batch, NN, g + 1);
  float acc = 0.f;
  for (int n = lo + part; n < hi; n += 16)
    acc += bf2f(h[(size_t)n * D + col]);
  atomicAdd(&hg[(size_t)g * (3 * D) + layer * D + col], acc);
}

// ---------------------------------------------------------------------------
// MFMA GEMM (+ piggy-backed pooling of the PREVIOUS layer's h).
// ---------------------------------------------------------------------------
constexpr int GEMM_B = NN / 64;  // 625

__global__ __launch_bounds__(256)
void gemm_pool(const ushort* __restrict__ A, const ushort* __restrict__ Wb,
               ushort* __restrict__ out, const ushort* __restrict__ hprev,
               const int* __restrict__ batch, float* __restrict__ hg,
               int layer) {
  const int b = blockIdx.x;
  if (b >= GEMM_B) {
    pool_body(b - GEMM_B, threadIdx.x, hprev, batch, hg, layer);
    return;
  }
  const int tid  = threadIdx.x;
  const int wave = tid >> 6, lane = tid & 63;
  const int n0 = b * 64 + wave * 16;
  const int r  = lane & 15, kg = lane >> 4;

  short8 afr[4];
  const ushort* arow = A + (size_t)(n0 + r) * D + kg * 8;
#pragma unroll
  for (int kt = 0; kt < 4; ++kt)
    afr[kt] = *(const short8*)(arow + kt * 32);

#pragma unroll
  for (int ct = 0; ct < 8; ++ct) {
    f32x4 acc = {0.f, 0.f, 0.f, 0.f};
    const ushort* wrow = Wb + (size_t)(ct * 16 + r) * D + kg * 8;
#pragma unroll
    for (int kt = 0; kt < 4; ++kt) {
      const short8 bfr = *(const short8*)(wrow + kt * 32);
      acc = __builtin_amdgcn_mfma_f32_16x16x32_bf16(afr[kt], bfr, acc, 0, 0, 0);
    }
#pragma unroll
    for (int q = 0; q < 4; ++q) {
      const int m = kg * 4 + q;
      out[(size_t)(n0 + m) * D + ct * 16 + r] = f2bf(acc[q]);
    }
  }
}

// standalone pool for the final layer
__global__ __launch_bounds__(256)
void pool_k(const ushort* __restrict__ h, const int* __restrict__ batch,
            float* __restrict__ hg, int layer) {
  pool_body(blockIdx.x, threadIdx.x, h, batch, hg, layer);
}

// ---------------------------------------------------------------------------
// Gather (CSR, bf16 rows) + PReLU. One wave per node; lane i loads 4B edge
// meta epk[lo+i]; broadcast via readlane; 16 independent row-gathers per
// batch (tail padded 0 -> src 0, w 0.0: L1-hit dummy loads contribute 0).
// NO fused pooling (round-7: +70µs/layer from hg atomics serialization).
// ---------------------------------------------------------------------------
__global__ __launch_bounds__(256)
void gather_prelu(const ushort* __restrict__ tmp, const int* __restrict__ off,
                  const unsigned* __restrict__ epk, const float* __restrict__ aP,
                  ushort* __restrict__ hb, float* __restrict__ hout) {
  const int wid  = (blockIdx.x * 256 + threadIdx.x) >> 6;
  const int lane = threadIdx.x & 63;
  if (wid >= NN) return;
  const int lo = off[wid], hi = off[wid + 1];
  const int deg = hi - lo;
  float ax = 0.f, ay = 0.f;

  for (int base = 0; base < deg; base += 64) {
    const int rem = deg - base;
    unsigned meta = 0u;
    if (lane < rem) meta = epk[lo + base + lane];
    const int cnt = rem < 64 ? rem : 64;
    for (int j0 = 0; j0 < cnt; j0 += 16) {
      unsigned v[16]; float w[16];
#pragma unroll
      for (int j = 0; j < 16; ++j) {
        const unsigned m = (unsigned)__builtin_amdgcn_readlane((int)meta, j0 + j);
        w[j] = __uint_as_float(m & 0xFFFF0000u);
        v[j] = *(const unsigned*)(tmp + (size_t)(m & 0xFFFFu) * D + lane * 2);
      }
#pragma unroll
      for (int j = 0; j < 16; ++j) {
        ax += __uint_as_float(v[j] << 16) * w[j];
        ay += __uint_as_float(v[j] & 0xFFFF0000u) * w[j];
      }
    }
  }
  const float alpha = aP[0];
  ax = ax >= 0.f ? ax : alpha * ax;
  ay = ay >= 0.f ? ay : alpha * ay;

  union { unsigned u; ushort s[2]; } pk;
  pk.s[0] = f2bf(ax); pk.s[1] = f2bf(ay);
  *(unsigned*)(hb + (size_t)wid * D + lane * 2) = pk.u;
  if (hout)
    *(float2*)(hout + (size_t)wid * D + lane * 2) = make_float2(ax, ay);
}

// ---------------------------------------------------------------------------
extern "C" void kernel_launch(void* const* d_in, const int* in_sizes, int n_in,
                              void* d_out, int out_size, void* d_ws, size_t ws_size,
                              hipStream_t stream) {
  const float* feat    = (const float*)d_in[0];
  const float* eweight = (const float*)d_in[1];
  const float* W[3]    = {(const float*)d_in[2], (const float*)d_in[3], (const float*)d_in[4]};
  const float* a[3]    = {(const float*)d_in[5], (const float*)d_in[6], (const float*)d_in[7]};
  const int*   eidx    = (const int*)d_in[8];
  const int*   batch   = (const int*)d_in[9];
  const int*   erow = eidx;
  const int*   ecol = eidx + NE;

  char* ws = (char*)d_ws;
  ushort*   tmp    = (ushort*)(ws);               // 10,240,000 B (bf16 NN x D)
  ushort*   hb     = (ushort*)(ws + 10240000);    // 10,240,000 B (bf16 h)
  ushort*   featb  = (ushort*)(ws + 20480000);    // 10,240,000 B (bf16 feat)
  int*      cnt    = (int*)(ws + 30720000);       //    160,000 B
  int*      bstate = (int*)(ws + 30880000);       //        160 B  (scan state)
  int*      ticket = (int*)(ws + 30880160);       //          4 B
  int*      off    = (int*)(ws + 30880192);       //    160,004 B
  int*      cur    = (int*)(ws + 31040256);       //    160,000 B
  unsigned* epk    = (unsigned*)(ws + 31200320);  //  2,560,000 B
  ushort*   Wb     = (ushort*)(ws + 33760320);    //     98,304 B  (3 x 128 x 128)

  float* hout = (float*)d_out;                 // NN x D (f32)
  float* hg   = hout + (size_t)NN * D;         // NG x 3D

  // zero cnt + bstate + ticket in one contiguous range
  hipMemsetAsync(cnt, 0, 160164, stream);

  hist_cvt<<<HIST_B + CVT_B + HGZ_B, 256, 0, stream>>>(
      ecol, cnt, feat, W[0], W[1], W[2], featb, Wb, hg);
  scan_onepass<<<SCAN_NB, SCAN_B, 0, stream>>>(cnt, off, cur, bstate, ticket);
  fill_k<<<(NE + 255) / 256, 256, 0, stream>>>(erow, ecol, eweight, cur, epk);

  const ushort* in = featb;
  for (int l = 0; l < 3; ++l) {
    const int grid = (l == 0) ? GEMM_B : GEMM_B + 1024;  // piggy-back pool(l-1)
    gemm_pool<<<grid, 256, 0, stream>>>(in, Wb + (size_t)l * D * D, tmp,
                                        hb, batch, hg, l - 1);
    gather_prelu<<<(NN * 64 + 255) / 256, 256, 0, stream>>>(
        tmp, off, epk, a[l], hb, (l == 2) ? hout : nullptr);
    in = hb;
  }
  pool_k<<<1024, 256, 0, stream>>>(hb, batch, hg, 2);
}